// Round 1
// baseline (317.081 us; speedup 1.0000x reference)
//
#include <hip/hip_runtime.h>
#include <math.h>

#define N_LEVELS 24
#define CAPACITY 262144u
#define CAP_MASK 0x3FFFFu

struct ScaleArg { float s[N_LEVELS]; };

__global__ __launch_bounds__(256)
void permuto_enc(const float* __restrict__ pos,
                 const float* __restrict__ lattice,
                 const float* __restrict__ rshift,
                 const float* __restrict__ anneal,
                 float* __restrict__ out,
                 ScaleArg sc, int npts)
{
#pragma clang fp contract(off)
    __shared__ float sh_shift[N_LEVELS][3];
    __shared__ float sh_ann[N_LEVELS];
    const int tid = threadIdx.x;
    if (tid < N_LEVELS) {
        sh_shift[tid][0] = rshift[tid * 3 + 0];
        sh_shift[tid][1] = rshift[tid * 3 + 1];
        sh_shift[tid][2] = rshift[tid * 3 + 2];
        sh_ann[tid] = anneal[tid];
    }
    __syncthreads();

    const int n = blockIdx.x * 256 + tid;
    if (n >= npts) return;

    const float p0 = pos[n * 3 + 0];
    const float p1 = pos[n * 3 + 1];
    const float p2 = pos[n * 3 + 2];

    // f32(INV_STD_DEV / sqrt((i+1)*(i+2))), INV_STD_DEV = 4*sqrt(2/3)
    const float sf0 = 2.3094010767585034f;
    const float sf1 = 1.3333333333333335f;
    const float sf2 = 0.9428090415820634f;

    const float2* __restrict__ tab = (const float2*)lattice;
    float2* __restrict__ outv = (float2*)out + (size_t)n * N_LEVELS;

    for (int l = 0; l < N_LEVELS; ++l) {
        const float scale = sc.s[l];
        // p/scale + shift  (true IEEE divide, matches np f32 op order)
        const float q0 = p0 / scale + sh_shift[l][0];
        const float q1 = p1 / scale + sh_shift[l][1];
        const float q2 = p2 / scale + sh_shift[l][2];
        const float cf0 = q0 * sf0;
        const float cf1 = q1 * sf1;
        const float cf2 = q2 * sf2;

        // elevated (matches reversed-cumsum order: rc1 = cf2+cf1; rc0 = rc1+cf0)
        const float rc1 = cf2 + cf1;
        const float el0 = rc1 + cf0;
        const float el1 = rc1 - cf0;          // rc1 - 1*cf0
        const float el2 = cf2 - 2.0f * cf1;
        const float el3 = 0.0f - 3.0f * cf2;

        // rem0 = round(el/4)*4  (rintf == np.round, half-to-even; /4 and *4 exact)
        float r0 = rintf(el0 * 0.25f) * 4.0f;
        float r1 = rintf(el1 * 0.25f) * 4.0f;
        float r2 = rintf(el2 * 0.25f) * 4.0f;
        float r3 = rintf(el3 * 0.25f) * 4.0f;

        const float d0 = el0 - r0;
        const float d1 = el1 - r1;
        const float d2 = el2 - r2;
        const float d3 = el3 - r3;

        // rank: for i<j, if d[i]<d[j] rank[i]++ else rank[j]++
        int k0 = 0, k1 = 0, k2 = 0, k3 = 0;
        if (d0 < d1) k0++; else k1++;
        if (d0 < d2) k0++; else k2++;
        if (d0 < d3) k0++; else k3++;
        if (d1 < d2) k1++; else k2++;
        if (d1 < d3) k1++; else k3++;
        if (d2 < d3) k2++; else k3++;

        const int s = (int)rintf((((r0 + r1) + r2) + r3) * 0.25f);
        k0 += s; k1 += s; k2 += s; k3 += s;

        if (k0 < 0) { k0 += 4; r0 += 4.0f; } else if (k0 > 3) { k0 -= 4; r0 -= 4.0f; }
        if (k1 < 0) { k1 += 4; r1 += 4.0f; } else if (k1 > 3) { k1 -= 4; r1 -= 4.0f; }
        if (k2 < 0) { k2 += 4; r2 += 4.0f; } else if (k2 > 3) { k2 -= 4; r2 -= 4.0f; }
        if (k3 < 0) { k3 += 4; r3 += 4.0f; } else if (k3 > 3) { k3 -= 4; r3 -= 4.0f; }

        const float dl0 = (el0 - r0) * 0.25f;
        const float dl1 = (el1 - r1) * 0.25f;
        const float dl2 = (el2 - r2) * 0.25f;
        const float dl3 = (el3 - r3) * 0.25f;

        // g[r] = delta of the coord whose rank == r  (rank is a permutation of 0..3)
        const float g0 = (k0 == 0 ? dl0 : 0.0f) + (k1 == 0 ? dl1 : 0.0f) + (k2 == 0 ? dl2 : 0.0f) + (k3 == 0 ? dl3 : 0.0f);
        const float g1 = (k0 == 1 ? dl0 : 0.0f) + (k1 == 1 ? dl1 : 0.0f) + (k2 == 1 ? dl2 : 0.0f) + (k3 == 1 ? dl3 : 0.0f);
        const float g2 = (k0 == 2 ? dl0 : 0.0f) + (k1 == 2 ? dl1 : 0.0f) + (k2 == 2 ? dl2 : 0.0f) + (k3 == 2 ? dl3 : 0.0f);
        const float g3 = (k0 == 3 ? dl0 : 0.0f) + (k1 == 3 ? dl1 : 0.0f) + (k2 == 3 ? dl2 : 0.0f) + (k3 == 3 ? dl3 : 0.0f);

        // weights: w0 = b0 + 1 + b4 = (g3 + 1) - g0 ; w1 = g2-g3 ; w2 = g1-g2 ; w3 = g0-g1
        const float w0 = g3 + 1.0f - g0;
        const float w1 = g2 - g3;
        const float w2 = g1 - g2;
        const float w3 = g0 - g1;

        const int i0 = (int)r0;
        const int i1 = (int)r1;
        const int i2 = (int)r2;

        float acc0 = 0.0f, acc1 = 0.0f;
        const unsigned lbase = (unsigned)l * CAPACITY;
#pragma unroll
        for (int r = 0; r < 4; ++r) {
            const int key0 = i0 + r - ((k0 > 3 - r) ? 4 : 0);
            const int key1 = i1 + r - ((k1 > 3 - r) ? 4 : 0);
            const int key2 = i2 + r - ((k2 > 3 - r) ? 4 : 0);
            const unsigned h = (unsigned)key0 * 2654435761u
                             ^ (unsigned)key1 * 805459861u
                             ^ (unsigned)key2 * 3674653429u;
            const unsigned idx = h & CAP_MASK;
            const float2 v = tab[lbase + idx];
            const float w = (r == 0) ? w0 : (r == 1) ? w1 : (r == 2) ? w2 : w3;
            acc0 += w * v.x;
            acc1 += w * v.y;
        }
        const float a = sh_ann[l];
        outv[l] = make_float2(acc0 * a, acc1 * a);
    }
}

extern "C" void kernel_launch(void* const* d_in, const int* in_sizes, int n_in,
                              void* d_out, int out_size, void* d_ws, size_t ws_size,
                              hipStream_t stream) {
    const float* pos     = (const float*)d_in[0];
    const float* lattice = (const float*)d_in[1];
    const float* rshift  = (const float*)d_in[2];
    const float* anneal  = (const float*)d_in[3];
    float* out = (float*)d_out;
    const int npts = in_sizes[0] / 3;

    // np.geomspace(1.0, 1e-4, 24).astype(f32): 10**(i * (-4/23)), endpoints pinned
    ScaleArg sc;
    for (int i = 0; i < N_LEVELS; ++i)
        sc.s[i] = (float)pow(10.0, (double)i * (-4.0 / 23.0));
    sc.s[0] = 1.0f;
    sc.s[N_LEVELS - 1] = 1e-4f;

    const int blocks = (npts + 255) / 256;
    permuto_enc<<<blocks, 256, 0, stream>>>(pos, lattice, rshift, anneal, out, sc, npts);
}